// Round 3
// baseline (90.785 us; speedup 1.0000x reference)
//
#include <hip/hip_runtime.h>

#define HIDDEN 64
#define NLAYERS 4
#define NZ 120
#define NZP 128          // padded histogram bins
#define DIM_H 256
#define DIM_G 65536
#define NB_HIST 512

// ws layout (bytes):
//   [0..256)                    float gfeat[64]
//   [1024..1024+512*128*4)      uint  part[NB_HIST][NZP]   (262144 B)
//   [WS_GRAW..+256KB)           float graw[65536]
#define WS_GF_OFF    0
#define WS_PART_OFF  1024
#define WS_GRAW_OFF  (1024 + NB_HIST * NZP * 4)

// ---------------- K1: histogram with inline int64 detection, per-block partials ----------------
__global__ void k_hist(const int* __restrict__ Z, int n, unsigned* __restrict__ part) {
    __shared__ unsigned h[NZP];
    for (int b = threadIdx.x; b < NZP; b += blockDim.x) h[b] = 0;

    // int64-materialized Z (little-endian, values < 120) => odd int32 words all zero.
    // Probe the first 64 odd words; (1/120)^64 false-positive odds for true int32.
    int t = threadIdx.x & 63;
    int probe = Z[2 * t + 1];
    unsigned long long ball = __ballot(probe != 0);
    bool is64 = (ball == 0ULL);

    __syncthreads();
    int stride = gridDim.x * blockDim.x;
    for (int i = blockIdx.x * blockDim.x + threadIdx.x; i < n; i += stride) {
        int v = is64 ? Z[2 * i] : Z[i];
        v = min(max(v, 0), NZ - 1);
        atomicAdd(&h[v], 1u);
    }
    __syncthreads();
    unsigned* slot = part + blockIdx.x * NZP;
    for (int b = threadIdx.x; b < NZP; b += blockDim.x) slot[b] = h[b];   // full overwrite
}

// ---------------- K2: reduce partials -> counts; 120 MLPs; gfeat (fp64); h-output ----------------
__global__ void __launch_bounds__(1024) k_mid(const unsigned* __restrict__ part,
                                              const float* __restrict__ embed,
                                              const float* __restrict__ Wtp,
                                              const float* __restrict__ w_h,
                                              const float* __restrict__ b_h,
                                              float* __restrict__ gf_out,
                                              float* __restrict__ out) {
    __shared__ unsigned counts[NZP];
    __shared__ float xs[16][HIDDEN];
    __shared__ double gsum[16][HIDDEN];
    __shared__ float gf[HIDDEN];
    __shared__ float hbuf[DIM_H];
    int tid = threadIdx.x;

    if (tid < NZP) counts[tid] = 0;
    __syncthreads();
    {   // counts[z] = sum_b part[b][z]
        int z = tid & (NZP - 1);
        int g = tid >> 7;                         // 8 groups
        unsigned s = 0;
        for (int b = g; b < NB_HIST; b += 8) s += part[b * NZP + z];
        atomicAdd(&counts[z], s);
    }
    __syncthreads();

    int w = tid >> 6, c = tid & 63;               // 16 waves, lane = channel
    double acc = 0.0;
    for (int r = 0; r < 8; ++r) {
        int z = r * 16 + w;                       // 0..127
        bool valid = (z < NZ);
        float x = valid ? embed[z * HIDDEN + c] : 0.f;
        for (int l = 0; l < NLAYERS; ++l) {
            xs[w][c] = x;
            __syncthreads();
            float u = 0.f;
            const float* W = Wtp + l * HIDDEN * HIDDEN;
            #pragma unroll
            for (int k = 0; k < HIDDEN; ++k) u += xs[w][k] * W[k * HIDDEN + c];
            u *= 0.125f;                          // * y0 * INV_SQRT_H
            x = u / (1.f + expf(-u));             // silu
            __syncthreads();
        }
        acc += (double)x * (double)(valid ? counts[z] : 0u);
    }
    gsum[w][c] = acc;
    __syncthreads();
    if (tid < HIDDEN) {
        double s = 0.0;
        #pragma unroll
        for (int ww = 0; ww < 16; ++ww) s += gsum[ww][tid];
        gf[tid] = (float)s;
        gf_out[tid] = (float)s;
    }
    __syncthreads();
    if (tid < DIM_H) {                            // h = gf @ w_h + b_h
        float a = b_h[tid];
        #pragma unroll
        for (int k = 0; k < HIDDEN; ++k) a += gf[k] * w_h[k * DIM_H + tid];
        hbuf[tid] = a;
    }
    __syncthreads();
    if (tid < DIM_H) {                            // symmetrize h
        int i = tid >> 4, j = tid & 15;
        out[tid] = 0.5f * (hbuf[tid] + hbuf[j * 16 + i]);
    }
}

// ---------------- K3: raw g = gfeat @ w_g + b_g ----------------
__global__ void k_graw(const float* __restrict__ gf_in, const float* __restrict__ w_g,
                       const float* __restrict__ b_g, float* __restrict__ graw) {
    __shared__ float gf[HIDDEN];
    if (threadIdx.x < HIDDEN) gf[threadIdx.x] = gf_in[threadIdx.x];
    __syncthreads();
    int p = blockIdx.x * blockDim.x + threadIdx.x;   // 0..65535
    float acc = b_g[p];
    #pragma unroll
    for (int c = 0; c < HIDDEN; ++c) acc += gf[c] * w_g[c * DIM_G + p];
    graw[p] = acc;
}

// ---------------- K4: 8-fold symmetrize g, write float32 output ----------------
__global__ void k_sym(const float* __restrict__ graw, float* __restrict__ out) {
    int q = blockIdx.x * blockDim.x + threadIdx.x;   // 0..65535
    int l = q & 15, k = (q >> 4) & 15, j = (q >> 8) & 15, i = (q >> 12) & 15;
    #define IDX4(a,b,c,d) ((((a)*16+(b))*16+(c))*16+(d))
    float s = graw[IDX4(i,j,k,l)] + graw[IDX4(j,i,k,l)]
            + graw[IDX4(i,j,l,k)] + graw[IDX4(j,i,l,k)]
            + graw[IDX4(k,l,i,j)] + graw[IDX4(l,k,i,j)]
            + graw[IDX4(k,l,j,i)] + graw[IDX4(l,k,j,i)];
    out[DIM_H + q] = s * 0.125f;
}

extern "C" void kernel_launch(void* const* d_in, const int* in_sizes, int n_in,
                              void* d_out, int out_size, void* d_ws, size_t ws_size,
                              hipStream_t stream) {
    const int*   Z     = (const int*)  d_in[0];
    // d_in[1] = pos (unused), d_in[2] = ghost (unused)
    const float* embed = (const float*)d_in[3];
    const float* Wtp   = (const float*)d_in[4];
    const float* w_h   = (const float*)d_in[5];
    const float* b_h   = (const float*)d_in[6];
    const float* w_g   = (const float*)d_in[7];
    const float* b_g   = (const float*)d_in[8];
    float* out = (float*)d_out;

    int n = in_sizes[0];                        // 1,000,000 nodes

    char* ws = (char*)d_ws;
    float*    gf    = (float*)   (ws + WS_GF_OFF);
    unsigned* part  = (unsigned*)(ws + WS_PART_OFF);
    float*    graw  = (float*)   (ws + WS_GRAW_OFF);

    k_hist<<<NB_HIST, 256, 0, stream>>>(Z, n, part);
    k_mid <<<1, 1024, 0, stream>>>(part, embed, Wtp, w_h, b_h, gf, out);
    k_graw<<<DIM_G / 256, 256, 0, stream>>>(gf, w_g, b_g, graw);
    k_sym <<<DIM_G / 256, 256, 0, stream>>>(graw, out);
}

// Round 4
// 22.251 us; speedup vs baseline: 4.0800x; 4.0800x over previous
//
#include <hip/hip_runtime.h>

#define HIDDEN 64
#define NLAYERS 4
#define NZ 120
#define NZP 128          // padded histogram bins
#define DIM_H 256
#define DIM_G 65536
#define NB_HIST 512

// ws layout (bytes):
//   [0..512)                    double gfeat[64]
//   [1024..1024+512*128*4)      uint  part[NB_HIST][NZP]   (262144 B)
//   [WS_GRAW..+256KB)           float graw[65536]
#define WS_GF_OFF    0
#define WS_PART_OFF  1024
#define WS_GRAW_OFF  (1024 + NB_HIST * NZP * 4)

// ---------------- K1: histogram (per-block partials) + gfeat zeroing ----------------
__global__ void k_hist(const int* __restrict__ Z, int n, unsigned* __restrict__ part,
                       double* __restrict__ gfeat) {
    if (blockIdx.x == 0 && threadIdx.x < HIDDEN) gfeat[threadIdx.x] = 0.0;

    __shared__ unsigned h[NZP];
    for (int b = threadIdx.x; b < NZP; b += blockDim.x) h[b] = 0;

    // int64-materialized Z (little-endian, values < 120) => odd int32 words all zero.
    // Probe 64 odd words; (1/120)^64 false-positive odds for true int32 data.
    int t = threadIdx.x & 63;
    int probe = Z[2 * t + 1];
    unsigned long long ball = __ballot(probe != 0);
    bool is64 = (ball == 0ULL);

    __syncthreads();
    int stride = gridDim.x * blockDim.x;
    for (int i = blockIdx.x * blockDim.x + threadIdx.x; i < n; i += stride) {
        int v = is64 ? Z[2 * i] : Z[i];
        v = min(max(v, 0), NZ - 1);
        atomicAdd(&h[v], 1u);
    }
    __syncthreads();
    unsigned* slot = part + blockIdx.x * NZP;
    for (int b = threadIdx.x; b < NZP; b += blockDim.x) slot[b] = h[b];   // full overwrite
}

// ---------------- K2: per-z count reduce + 4-layer MLP; fp64 atomic gfeat ----------------
__global__ void __launch_bounds__(64) k_mlp(const unsigned* __restrict__ part,
                                            const float* __restrict__ embed,
                                            const float* __restrict__ Wtp,
                                            double* __restrict__ gfeat) {
    int z = blockIdx.x;            // 0..119
    int c = threadIdx.x;           // 0..63

    // counts[z] = sum over 512 block-partials (L2-resident, 8 loads/lane)
    unsigned s = 0;
    #pragma unroll
    for (int b = 0; b < NB_HIST / 64; ++b) s += part[(b * 64 + c) * NZP + z];
    #pragma unroll
    for (int off = 32; off > 0; off >>= 1) s += __shfl_down(s, off, 64);
    unsigned cnt = __shfl(s, 0, 64);

    __shared__ float xs[HIDDEN];
    float x = embed[z * HIDDEN + c];
    for (int l = 0; l < NLAYERS; ++l) {
        xs[c] = x;
        __syncthreads();
        const float* W = Wtp + l * HIDDEN * HIDDEN;
        float u = 0.f;
        #pragma unroll
        for (int k = 0; k < HIDDEN; ++k) u += xs[k] * W[k * HIDDEN + c];
        u *= 0.125f;                       // * y0 * INV_SQRT_H
        x = u / (1.f + expf(-u));          // silu
        __syncthreads();
    }
    atomicAdd(&gfeat[c], (double)x * (double)cnt);
}

// ---------------- K3: blocks 0..255: graw = gfeat @ w_g + b_g; block 256: h output ----
__global__ void k_graw(const double* __restrict__ gfeat, const float* __restrict__ w_g,
                       const float* __restrict__ b_g, const float* __restrict__ w_h,
                       const float* __restrict__ b_h, float* __restrict__ graw,
                       float* __restrict__ out) {
    __shared__ float gf[HIDDEN];
    if (threadIdx.x < HIDDEN) gf[threadIdx.x] = (float)gfeat[threadIdx.x];
    __syncthreads();

    if (blockIdx.x < DIM_G / 256) {
        int p = blockIdx.x * blockDim.x + threadIdx.x;   // 0..65535
        float acc = b_g[p];
        #pragma unroll
        for (int c = 0; c < HIDDEN; ++c) acc += gf[c] * w_g[c * DIM_G + p];
        graw[p] = acc;
    } else {
        __shared__ float hbuf[DIM_H];
        int p = threadIdx.x;                 // 0..255
        float a = b_h[p];
        #pragma unroll
        for (int c = 0; c < HIDDEN; ++c) a += gf[c] * w_h[c * DIM_H + p];
        hbuf[p] = a;
        __syncthreads();
        int i = p >> 4, j = p & 15;
        out[p] = 0.5f * (hbuf[p] + hbuf[j * 16 + i]);
    }
}

// ---------------- K4: 8-fold symmetrize g, write float32 output ----------------
__global__ void k_sym(const float* __restrict__ graw, float* __restrict__ out) {
    int q = blockIdx.x * blockDim.x + threadIdx.x;   // 0..65535
    int l = q & 15, k = (q >> 4) & 15, j = (q >> 8) & 15, i = (q >> 12) & 15;
    #define IDX4(a,b,c,d) ((((a)*16+(b))*16+(c))*16+(d))
    float s = graw[IDX4(i,j,k,l)] + graw[IDX4(j,i,k,l)]
            + graw[IDX4(i,j,l,k)] + graw[IDX4(j,i,l,k)]
            + graw[IDX4(k,l,i,j)] + graw[IDX4(l,k,i,j)]
            + graw[IDX4(k,l,j,i)] + graw[IDX4(l,k,j,i)];
    out[DIM_H + q] = s * 0.125f;
}

extern "C" void kernel_launch(void* const* d_in, const int* in_sizes, int n_in,
                              void* d_out, int out_size, void* d_ws, size_t ws_size,
                              hipStream_t stream) {
    const int*   Z     = (const int*)  d_in[0];
    // d_in[1] = pos (unused), d_in[2] = ghost (unused)
    const float* embed = (const float*)d_in[3];
    const float* Wtp   = (const float*)d_in[4];
    const float* w_h   = (const float*)d_in[5];
    const float* b_h   = (const float*)d_in[6];
    const float* w_g   = (const float*)d_in[7];
    const float* b_g   = (const float*)d_in[8];
    float* out = (float*)d_out;

    int n = in_sizes[0];                        // 1,000,000 nodes

    char* ws = (char*)d_ws;
    double*   gfeat = (double*)  (ws + WS_GF_OFF);
    unsigned* part  = (unsigned*)(ws + WS_PART_OFF);
    float*    graw  = (float*)   (ws + WS_GRAW_OFF);

    k_hist<<<NB_HIST, 256, 0, stream>>>(Z, n, part, gfeat);
    k_mlp <<<NZ, 64, 0, stream>>>(part, embed, Wtp, gfeat);
    k_graw<<<DIM_G / 256 + 1, 256, 0, stream>>>(gfeat, w_g, b_g, w_h, b_h, graw, out);
    k_sym <<<DIM_G / 256, 256, 0, stream>>>(graw, out);
}